// Round 1
// 645.611 us; speedup vs baseline: 1.0257x; 1.0257x over previous
//
#include <hip/hip_runtime.h>
#include <math.h>

#define BB 256
#define TT 1024
#define KK 128
#define NTHR 512
#define CHUNK 16
#define NCHUNK (TT / CHUNK)   // 64
#define QSTR 40               // ushorts per q-quarter (80 B): quarters at 0,80,160,240 B -> disjoint banks

__global__ void zero_out_kernel(float* out) { out[0] = 0.0f; }

#define LOBF(u) __uint_as_float((u) << 16)
#define HIBF(u) __uint_as_float((u) & 0xFFFF0000u)

// E init: V gets exp(trans[I0..I0+3][j]) (column j, rows I0..)
#define LDE(V, I0) { V.x = expf(tcol[(size_t)(I0) * KK]); \
                     V.y = expf(tcol[(size_t)((I0) + 1) * KK]); \
                     V.z = expf(tcol[(size_t)((I0) + 2) * KK]); \
                     V.w = expf(tcol[(size_t)((I0) + 3) * KK]); }

// 8 bf16 p-values in uint4 V against 8 E values in EA,EB
#define FMA8(V, EA, EB) { \
    z0 = fmaf(LOBF(V.x), EA.x, z0); z1 = fmaf(HIBF(V.x), EA.y, z1); \
    z2 = fmaf(LOBF(V.y), EA.z, z2); z3 = fmaf(HIBF(V.y), EA.w, z3); \
    z0 = fmaf(LOBF(V.z), EB.x, z0); z1 = fmaf(HIBF(V.z), EB.y, z1); \
    z2 = fmaf(LOBF(V.w), EB.z, z2); z3 = fmaf(HIBF(V.w), EB.w, z3); }

// LGKM-only barrier: LDS visibility is the only cross-wave dependency in the hot
// loop; leaving vmcnt outstanding lets the emission prefetch span the whole chunk
// (T4: never drain vmcnt in the main loop).
#define BARSYNC() { asm volatile("s_waitcnt lgkmcnt(0)" ::: "memory"); \
                    __builtin_amdgcn_s_barrier(); \
                    asm volatile("" ::: "memory"); }

// One block per batch. 512 threads (8 waves = 2 waves/SIMD for latency hiding):
// j = tid>>2 (output state), q = tid&3 (i-quarter, 32 i-values each).
// Forward recursion in exp space; p stored bf16 in LDS, E = exp(trans) in 8 named
// float4 registers per thread, X = exp(emit) double-buffered in LDS.
// Renorm by exact power-of-2 from bf16 p_prev[0]'s exponent (lag-0 via broadcast read).
__global__ __launch_bounds__(NTHR, 2) void crf_kernel(
    const float* __restrict__ inputs,      // B*T*K fp32
    const float* __restrict__ trans,       // K*K fp32
    const int* __restrict__ tags,          // B*T int32 view
    const int* __restrict__ mask,          // B*T int32
    float* __restrict__ out)               // scalar
{
    __shared__ __align__(16) unsigned short pbuf[2][4 * QSTR]; // bf16 p, quarters 80B apart
    __shared__ __align__(16) float ebuf[2][CHUNK * KK];        // exp(emissions)
    __shared__ float mbuf[2][CHUNK];
    __shared__ float scratch[16];

    const int tid = threadIdx.x;
    const int q   = tid & 3;
    const int j   = tid >> 2;
    const int b   = blockIdx.x;

    const float* binp = inputs + (size_t)b * TT * KK;
    const int* bmask  = mask + (size_t)b * TT;
    const int* btags  = tags + (size_t)b * TT;

    // ---- E in 8 named float4s: i = q*32 + 4*blk + {0..3} ----
    const float* tcol = trans + j;
    const int ib = q * 32;
    float4 E0, E1, E2, E3, E4, E5, E6, E7;
    LDE(E0, ib + 0)  LDE(E1, ib + 4)
    LDE(E2, ib + 8)  LDE(E3, ib + 12)
    LDE(E4, ib + 16) LDE(E5, ib + 20)
    LDE(E6, ib + 24) LDE(E7, ib + 28)

    // ---- stage chunk 0 of emissions as X = exp(e), + mask ----
    {
        float4 e4 = ((const float4*)binp)[tid];   // 512 * 4 = 2048 = CHUNK*KK floats
        e4.x = __expf(e4.x); e4.y = __expf(e4.y);
        e4.z = __expf(e4.z); e4.w = __expf(e4.w);
        ((float4*)ebuf[0])[tid] = e4;
    }
    if (tid < CHUNK) mbuf[0][tid] = (float)bmask[tid];
    BARSYNC();

    // ---- t = 0: p = exp(alpha0) = X[0][j], m = 0 ----
    float pcur = ebuf[0][j];
    int m_int = 0;
    if (q == 0) {
        unsigned bits = __float_as_uint(pcur);
        unsigned r = (bits + 0x7FFFu + ((bits >> 16) & 1u)) >> 16;   // RNE to bf16
        pbuf[0][(j >> 5) * QSTR + (j & 31)] = (unsigned short)r;
    }
    BARSYNC();

    for (int c = 0; c < NCHUNK; ++c) {
        // prefetch next emission chunk into registers (raw e; exp applied at store)
        float4 epre; int mpre = 0;
        if (c + 1 < NCHUNK) {
            epre = ((const float4*)(binp + (size_t)(c + 1) * CHUNK * KK))[tid];
            if (tid < CHUNK) mpre = bmask[(c + 1) * CHUNK + tid];
        }
        const float* eb = ebuf[c & 1];
        const float* mb = mbuf[c & 1];
        const int s0 = (c == 0) ? 1 : 0;
        for (int s = s0; s < CHUNK; ++s) {
            const int t = c * CHUNK + s;
            const uint4* pr4 = (const uint4*)(pbuf[(t - 1) & 1] + q * QSTR);
            uint4 v0 = pr4[0], v1 = pr4[1], v2 = pr4[2], v3 = pr4[3];
            float z0 = 0.f, z1 = 0.f, z2 = 0.f, z3 = 0.f;
            FMA8(v0, E0, E1) FMA8(v1, E2, E3)
            FMA8(v2, E4, E5) FMA8(v3, E6, E7)
            float z = (z0 + z1) + (z2 + z3);
            z += __shfl_xor(z, 1);                 // combine the four i-quarters
            z += __shfl_xor(z, 2);
            float X  = eb[s * KK + j];
            float mi = mb[s];
            float pn = (mi != 0.0f) ? z * X : pcur;   // mask-hold (mi in {0,1})
            // renorm: exact pow2 from bf16 p_prev[q*32]'s exponent.
            // Only q==0 lanes (anchor p[0]) feed the stored chain + final answer;
            // q!=0 lanes carry consistent ghost chains that are never read.
            unsigned u0 = v0.x << 16;
            int Ex = (int)((u0 >> 23) & 255u) - 127;
            float sc = __uint_as_float((unsigned)(127 - Ex) << 23);   // 2^-Ex
            pcur = pn * sc;
            m_int += Ex;
            if (q == 0) {
                unsigned bits = __float_as_uint(pcur);
                unsigned r = (bits + 0x7FFFu + ((bits >> 16) & 1u)) >> 16;
                pbuf[t & 1][(j >> 5) * QSTR + (j & 31)] = (unsigned short)r;
            }
            BARSYNC();
        }
        if (c + 1 < NCHUNK) {
            epre.x = __expf(epre.x); epre.y = __expf(epre.y);
            epre.z = __expf(epre.z); epre.w = __expf(epre.w);
            ((float4*)ebuf[(c + 1) & 1])[tid] = epre;
            if (tid < CHUNK) mbuf[(c + 1) & 1][tid] = (float)mpre;
            BARSYNC();
        }
    }

    // ---- denominator: LSE_j(alpha_j); alpha valid on q==0 lanes only ----
    float a = (q == 0) ? ((float)m_int * 0.69314718055994531f + logf(pcur))
                       : -INFINITY;
    float v = a;
#pragma unroll
    for (int o = 1; o < 64; o <<= 1) v = fmaxf(v, __shfl_xor(v, o));
    if ((tid & 63) == 0) scratch[tid >> 6] = v;
    __syncthreads();
    float mx = fmaxf(fmaxf(fmaxf(scratch[0], scratch[1]), fmaxf(scratch[2], scratch[3])),
                     fmaxf(fmaxf(scratch[4], scratch[5]), fmaxf(scratch[6], scratch[7])));
    float ev = (q == 0) ? __expf(a - mx) : 0.0f;
#pragma unroll
    for (int o = 1; o < 64; o <<= 1) ev += __shfl_xor(ev, o);
    __syncthreads();
    if ((tid & 63) == 0) scratch[tid >> 6] = ev;
    __syncthreads();
    float den = mx + logf(((scratch[0] + scratch[1]) + (scratch[2] + scratch[3]))
                        + ((scratch[4] + scratch[5]) + (scratch[6] + scratch[7])));

    // ---- numerator (gold-path score) ----
    float numpart = 0.0f, maskpart = 0.0f;
#pragma unroll
    for (int kk = 0; kk < TT / NTHR; ++kk) {   // 2 iterations
        int t = tid + NTHR * kk;
        int tg = btags[t];
        float mf = (float)bmask[t];
        maskpart += mf;
        if (t < TT - 1) {
            int tg1   = btags[t + 1];
            float mf1 = (float)bmask[t + 1];
            numpart += trans[tg * KK + tg1] * mf1;
            numpart += binp[(size_t)t * KK + tg] * mf;
        }
    }
#pragma unroll
    for (int o = 1; o < 64; o <<= 1) numpart += __shfl_xor(numpart, o);
#pragma unroll
    for (int o = 1; o < 64; o <<= 1) maskpart += __shfl_xor(maskpart, o);
    __syncthreads();
    if ((tid & 63) == 0) {
        scratch[tid >> 6]       = numpart;
        scratch[8 + (tid >> 6)] = maskpart;
    }
    __syncthreads();
    if (tid == 0) {
        float num  = ((scratch[0] + scratch[1]) + (scratch[2] + scratch[3]))
                   + ((scratch[4] + scratch[5]) + (scratch[6] + scratch[7]));
        float msum = ((scratch[8] + scratch[9]) + (scratch[10] + scratch[11]))
                   + ((scratch[12] + scratch[13]) + (scratch[14] + scratch[15]));
        int last_idx = (int)msum - 1;
        int ltag = btags[last_idx];
        num += binp[(size_t)(TT - 1) * KK + ltag] * (float)bmask[TT - 1];
        atomicAdd(out, num - den);
    }
}

extern "C" void kernel_launch(void* const* d_in, const int* in_sizes, int n_in,
                              void* d_out, int out_size, void* d_ws, size_t ws_size,
                              hipStream_t stream) {
    const float* inputs = (const float*)d_in[0];
    const float* trans  = (const float*)d_in[1];
    const int* tagsp    = (const int*)d_in[2];
    const int* maskp    = (const int*)d_in[3];
    float* out          = (float*)d_out;
    zero_out_kernel<<<1, 1, 0, stream>>>(out);
    crf_kernel<<<BB, NTHR, 0, stream>>>(inputs, trans, tagsp, maskp, out);
}